// Round 3
// baseline (666.048 us; speedup 1.0000x reference)
//
#include <hip/hip_runtime.h>

// PluginEmbedding: CSR sparse-embedding lookup + per-row sum combine.
//
// V3: degenerate-CSR fast path. A 2-launch prologue detects row_offsets ==
// arange(n_rows+1) (exactly 1 nnz/row) and stores a flag in d_ws. The main
// kernel then takes a uniform branch:
//   fast:    idx = vals[row]  (NO row_offsets loads, 2-level chain, U=8 ->
//            8 KB of independent table gathers in flight per wave)
//   general: full CSR start..end sum (U=8 to keep the row mapping identical)
// Output is written with nontemporal stores (write-once data).
//
// Layout: 32 lanes per row, lane c handles float4 #c of the 128-float row.
// Wave = 64 lanes = row pair per unroll step; each wave owns 16 consecutive
// rows -> every load/store touches contiguous 512 B segments.

#define ROW_F4 32  // 128 floats = 32 float4 per row
#define UF 8       // rows per thread, fast path (per half-wave)

typedef float f32x4 __attribute__((ext_vector_type(4)));

__global__ void eb_flag_init(int* flag) { *flag = 1; }

__global__ __launch_bounds__(256) void eb_flag_check(
    const int* __restrict__ ro, int n, int* flag)
{
    int stride = gridDim.x * blockDim.x;
    for (int i = blockIdx.x * blockDim.x + threadIdx.x; i <= n; i += stride) {
        if (ro[i] != i) { *flag = 0; return; }
    }
}

__global__ __launch_bounds__(256) void plugin_embedding_gather(
    const f32x4* __restrict__ table,
    const int*   __restrict__ row_offsets,
    const int*   __restrict__ vals,
    f32x4*       __restrict__ out,
    int n_rows,
    const int*   __restrict__ flag)
{
    int t    = blockIdx.x * blockDim.x + threadIdx.x;
    int lane = t & 63;
    int col  = lane & 31;   // float4 slot within the row
    int half = lane >> 5;   // which row of the wave's pair
    long long wid = t >> 6; // global wave id
    int base = (int)(wid * (2 * UF)) + half;  // rows: base, base+2, ...

    bool fast = (flag != nullptr) && (*flag != 0);  // wave-uniform

    if (fast) {
        // ---- degenerate CSR: pure gather, no offsets, batched levels ----
        int idx[UF];
        #pragma unroll
        for (int u = 0; u < UF; ++u) {
            int r = base + 2 * u;
            idx[u] = (r < n_rows) ? vals[r] : -1;
        }
        f32x4 acc[UF];
        #pragma unroll
        for (int u = 0; u < UF; ++u) {
            if (idx[u] >= 0) acc[u] = table[(size_t)idx[u] * ROW_F4 + col];
            else             acc[u] = (f32x4)(0.f);
        }
        #pragma unroll
        for (int u = 0; u < UF; ++u) {
            int r = base + 2 * u;
            if (r < n_rows)
                __builtin_nontemporal_store(acc[u], &out[(size_t)r * ROW_F4 + col]);
        }
    } else {
        // ---- general CSR sum (same 16-rows-per-wave mapping) ----
        int s[UF], e[UF];
        #pragma unroll
        for (int u = 0; u < UF; ++u) {
            int r = base + 2 * u;
            if (r < n_rows) { s[u] = row_offsets[r]; e[u] = row_offsets[r + 1]; }
            else            { s[u] = 0; e[u] = 0; }
        }
        int idx[UF];
        #pragma unroll
        for (int u = 0; u < UF; ++u)
            idx[u] = (s[u] < e[u]) ? vals[s[u]] : -1;
        f32x4 acc[UF];
        #pragma unroll
        for (int u = 0; u < UF; ++u) {
            if (idx[u] >= 0) acc[u] = table[(size_t)idx[u] * ROW_F4 + col];
            else             acc[u] = (f32x4)(0.f);
        }
        #pragma unroll
        for (int u = 0; u < UF; ++u) {
            for (int j = s[u] + 1; j < e[u]; ++j) {
                int id2 = vals[j];
                acc[u] += table[(size_t)id2 * ROW_F4 + col];
            }
        }
        #pragma unroll
        for (int u = 0; u < UF; ++u) {
            int r = base + 2 * u;
            if (r < n_rows)
                __builtin_nontemporal_store(acc[u], &out[(size_t)r * ROW_F4 + col]);
        }
    }
}

extern "C" void kernel_launch(void* const* d_in, const int* in_sizes, int n_in,
                              void* d_out, int out_size, void* d_ws, size_t ws_size,
                              hipStream_t stream) {
    const f32x4* table       = (const f32x4*)d_in[0];
    const int*   row_offsets = (const int*)d_in[1];
    const int*   vals        = (const int*)d_in[2];
    f32x4*       out         = (f32x4*)d_out;

    // out_size = n_rows * 128 floats
    int n_rows = out_size / 128;

    int* flag = (ws_size >= sizeof(int)) ? (int*)d_ws : nullptr;
    if (flag) {
        eb_flag_init<<<1, 1, 0, stream>>>(flag);
        int cgrid = 416;  // 416*256 ~ 106k threads, 2 strides over 213k ints
        eb_flag_check<<<cgrid, 256, 0, stream>>>(row_offsets, n_rows, flag);
    }

    // One wave handles 2*UF rows.
    long long waves         = ((long long)n_rows + 2 * UF - 1) / (2 * UF);
    long long total_threads = waves * 64;
    int block = 256;
    int grid  = (int)((total_threads + block - 1) / block);

    plugin_embedding_gather<<<grid, block, 0, stream>>>(
        table, row_offsets, vals, out, n_rows, flag);
}

// Round 4
// 630.964 us; speedup vs baseline: 1.0556x; 1.0556x over previous
//
#include <hip/hip_runtime.h>

// PluginEmbedding: CSR sparse-embedding lookup + per-row sum combine.
//
// V4 = CALIBRATION build. Structure is V2b (best measured: 609.5 us), plus a
// second hash-randomized table gather per row whose result is kept live with
// an empty asm() but never stored. This exactly doubles the kernel's random
// 512 B gather work without changing the output, so:
//     dur_us(V4) - dur_us(V2b)  ~=  the gather phase's true duration.
// Purpose: the timed region contains ~320 us of harness fill dispatches and
// our kernel has never appeared in the top-5, so we cannot see its duration
// directly. Three structural variants (1-row, 4-row MLP, 8-row fast path)
// all produced identical totals -> either the kernel is tiny (harness floor)
// or it is bound by a per-access cost (TLB) that MLP cannot hide. The delta
// this build produces discriminates the two.

#define ROW_F4 32  // 128 floats = 32 float4 per row
#define U 4        // rows per thread (per half-wave)

typedef float f32x4 __attribute__((ext_vector_type(4)));

__global__ __launch_bounds__(256) void plugin_embedding_gather(
    const f32x4* __restrict__ table,
    const int*   __restrict__ row_offsets,
    const int*   __restrict__ vals,
    f32x4*       __restrict__ out,
    int n_rows,
    int n_vocab)
{
    int t    = blockIdx.x * blockDim.x + threadIdx.x;
    int lane = t & 63;
    int col  = lane & 31;   // float4 slot within the row
    int half = lane >> 5;   // which row of the wave's pair
    long long wid = t >> 6; // global wave id
    int base = (int)(wid * (2 * U)) + half;  // rows: base, base+2, ..., base+2(U-1)

    int row[U], s[U], e[U], idx[U];
    bool live[U];

    // Level 1: batch all row_offsets loads
    #pragma unroll
    for (int u = 0; u < U; ++u) {
        row[u]  = base + 2 * u;
        live[u] = (row[u] < n_rows);
        if (live[u]) {
            s[u] = row_offsets[row[u]];
            e[u] = row_offsets[row[u] + 1];
        } else {
            s[u] = 0; e[u] = 0;
        }
    }

    // Level 2: batch all first-index loads
    #pragma unroll
    for (int u = 0; u < U; ++u)
        idx[u] = (s[u] < e[u]) ? vals[s[u]] : -1;

    // Level 3: batch all table-row gathers (the REAL work)
    f32x4 acc[U];
    #pragma unroll
    for (int u = 0; u < U; ++u) {
        if (idx[u] >= 0) {
            acc[u] = table[(size_t)idx[u] * ROW_F4 + col];
        } else {
            acc[u] = (f32x4)(0.f);
        }
    }

    // CALIBRATION load: one extra hash-randomized row gather per row.
    // Kept live via empty asm so the compiler cannot DCE it; never stored.
    #pragma unroll
    for (int u = 0; u < U; ++u) {
        if (idx[u] >= 0) {
            unsigned h = (unsigned)idx[u] * 2654435761u;
            int idx2 = (int)(h % (unsigned)n_vocab);
            f32x4 v2 = table[(size_t)idx2 * ROW_F4 + col];
            asm volatile("" :: "v"(v2.x), "v"(v2.y), "v"(v2.z), "v"(v2.w));
        }
    }

    // General CSR tail (never taken when nnz==1/row, kept for robustness)
    #pragma unroll
    for (int u = 0; u < U; ++u) {
        for (int j = s[u] + 1; j < e[u]; ++j) {
            int id2 = vals[j];
            acc[u] += table[(size_t)id2 * ROW_F4 + col];
        }
    }

    // Stores: write-once output, nontemporal
    #pragma unroll
    for (int u = 0; u < U; ++u) {
        if (live[u]) {
            __builtin_nontemporal_store(acc[u], &out[(size_t)row[u] * ROW_F4 + col]);
        }
    }
}

extern "C" void kernel_launch(void* const* d_in, const int* in_sizes, int n_in,
                              void* d_out, int out_size, void* d_ws, size_t ws_size,
                              hipStream_t stream) {
    const f32x4* table       = (const f32x4*)d_in[0];
    const int*   row_offsets = (const int*)d_in[1];
    const int*   vals        = (const int*)d_in[2];
    f32x4*       out         = (f32x4*)d_out;

    // sizes are in elements: out_size = n_rows*128 floats, in_sizes[0] = vocab*128 floats
    int n_rows  = out_size / 128;
    int n_vocab = in_sizes[0] / 128;
    if (n_vocab <= 0) n_vocab = 1;

    // One wave handles 2*U rows.
    long long waves         = ((long long)n_rows + 2 * U - 1) / (2 * U);
    long long total_threads = waves * 64;
    int block = 256;
    int grid  = (int)((total_threads + block - 1) / block);

    plugin_embedding_gather<<<grid, block, 0, stream>>>(
        table, row_offsets, vals, out, n_rows, n_vocab);
}